// Round 2
// 651.411 us; speedup vs baseline: 1.1655x; 1.1655x over previous
//
#include <hip/hip_runtime.h>
#include <cfloat>
#include <math.h>

// Problem constants
constexpr int H_  = 6;
constexpr int C_  = 64;
constexpr int OV_ = 4;
constexpr int G_  = 3;
constexpr int NVQ_ = 6;
constexpr int K_  = 1024;
constexpr int D_  = 8;
constexpr int B_  = 32;
constexpr int W_  = 2400;
constexpr int T_  = 600;          // W/OV
constexpr int NPOS_ = B_ * T_;    // 19200
constexpr int FIX_ = H_ * C_;     // 384
constexpr int GD_ = 512;

// Output layout (floats, concatenated in return order)
constexpr size_t OUT_ZQ   = 0;
constexpr size_t OUT_IDX  = (size_t)B_ * H_ * W_ * C_;             // 29491200
constexpr size_t OUT_LOSS = OUT_IDX + (size_t)B_ * NVQ_ * G_ * T_; // 29836800

// Workspace layout (bytes) — IDENTICAL to the 758 µs baseline layout.
constexpr size_t WS_EN   = 0;                                   // double[18432*8] transposed planes [gi*8+d][k]
constexpr size_t WS_ZD   = WS_EN + (size_t)G_*NVQ_*K_*D_*8;     // double[3*19200*8]
constexpr size_t WS_LOSS = WS_ZD + (size_t)G_*NPOS_*D_*8;       // double[8]
constexpr size_t WS_ZQ   = WS_LOSS + 64;                        // float[3*19200*8]

// ---------------------------------------------------------------------------
// K1: normalize codebooks (fp64) into transposed layout en[(gi*8+d)*1024 + k];
//     also zero the loss accumulator. (identical to baseline)
__global__ __launch_bounds__(256) void k1_norm_cb(const float* __restrict__ cb,
                                                  double* __restrict__ en,
                                                  double* __restrict__ loss) {
    int tid = blockIdx.x * 256 + threadIdx.x;
    if (tid == 0) loss[0] = 0.0;
    if (tid >= G_ * NVQ_ * K_) return;
    int k  = tid & (K_ - 1);
    int gi = tid >> 10;               // 0..17  (g*6+i)
    const float* row = cb + ((size_t)gi * K_ + k) * D_;
    double v[D_];
    double ss = 0.0;
#pragma unroll
    for (int d = 0; d < D_; d++) { v[d] = (double)row[d]; ss += v[d] * v[d]; }
    double n = sqrt(ss);
    if (n < 1e-12) n = 1e-12;
#pragma unroll
    for (int d = 0; d < D_; d++)
        en[((size_t)gi * D_ + d) * K_ + k] = v[d] / n;   // division to mimic ref
}

// ---------------------------------------------------------------------------
// K2: fold (pre_process) + proj_down with fp64 accumulation. (unchanged)
constexpr int PSTR_ = 1548;
constexpr int OVS_  = 388;

__global__ __launch_bounds__(256) void k2_fold_pd(const float* __restrict__ ze,
                                                  const float* __restrict__ pd,
                                                  double* __restrict__ zd) {
    __shared__ __align__(16) float zf[8 * PSTR_];
    int tid  = threadIdx.x;
    int pos0 = blockIdx.x * 8;
#pragma unroll
    for (int it = 0; it < 12; it++) {
        int slot = it * 256 + tid;
        int seg  = slot >> 6;
        int li   = slot & 63;
        int p = seg / 6, h = seg - p * 6;
        int pos = pos0 + p;
        int b = pos / T_, t = pos - b * T_;
        const float4 vv = *(const float4*)(ze + ((size_t)((b * H_ + h) * W_ + 4 * t)) * C_ + li * 4);
        int ov = li >> 4;
        int c0 = (li & 15) * 4;
        int base = p * PSTR_ + ov * OVS_ + h;
        zf[base + (c0 + 0) * 6] = vv.x;
        zf[base + (c0 + 1) * 6] = vv.y;
        zf[base + (c0 + 2) * 6] = vv.z;
        zf[base + (c0 + 3) * 6] = vv.w;
    }
    __syncthreads();
    if (tid < 192) {
        int p = tid / 24;
        int combo = tid - p * 24;
        int g = combo >> 3, d = combo & 7;
        const float* pdp = pd + ((size_t)g * D_ + d) * GD_;
        int lbase = p * PSTR_;
        double acc = 0.0;
        for (int jj = 0; jj < GD_; jj += 4) {
            int gd  = g * GD_ + jj;
            int ov  = gd / FIX_;
            int rem = gd - ov * FIX_;
            float4 zv = *(const float4*)&zf[lbase + ov * OVS_ + rem];
            float4 pv = *(const float4*)&pdp[jj];
            acc = fma((double)pv.x, (double)zv.x, acc);
            acc = fma((double)pv.y, (double)zv.y, acc);
            acc = fma((double)pv.z, (double)zv.z, acc);
            acc = fma((double)pv.w, (double)zv.w, acc);
        }
        zd[((size_t)g * NPOS_ + pos0 + p) * D_ + d] = acc;
    }
}

// ---------------------------------------------------------------------------
// K3: residual VQ. fp32 screening of all 1024 codewords (top-1 + top-2 value)
// with a provable margin test; exact fp64 rescan only when the fp32 gap can't
// certify the winner (rare, wave-uniform branch). Residual kept exact in fp64,
// DISTRIBUTED across lanes (lane l<32 holds (m=l>>3, d=l&7)); every lane keeps
// an fp32 replicated copy for the dot products, refreshed via shuffles each
// stream. The 32 KB fp32 LDS codebook is built by converting the fp64 planes
// during staging (no extra workspace region). Block: 512 threads (8 waves),
// one group, 32 positions (4 chains/wave).
__global__ __launch_bounds__(512, 4) void k3_rvq(const double* __restrict__ en64,
                                                 const double* __restrict__ zd,
                                                 float* __restrict__ zq,
                                                 double* __restrict__ loss,
                                                 float* __restrict__ out_idx) {
    __shared__ __align__(16) float2 en_s[4 * K_];    // 32 KB: planes dp=0..3 over k, (d=2dp, 2dp+1)
    __shared__ double ls[8];
    int tid  = threadIdx.x;
    int wv   = tid >> 6, lane = tid & 63;
    int g     = blockIdx.x / 600;
    int chunk = blockIdx.x - g * 600;
    int mypos0 = chunk * 32 + wv * 4;
    size_t zdbase = ((size_t)g * NPOS_ + mypos0) * D_;

    const double* en64g = en64 + (size_t)g * NVQ_ * D_ * K_;

    // distributed exact state: lane l<32 holds residual element (m=l>>3, d=l&7)
    double zd0 = 0.0, r64 = 0.0;
    if (lane < 32) { zd0 = zd[zdbase + lane]; r64 = zd0; }
    // fp32 replicated copy for screening
    float r32[4][8];
    {
        float fr = (float)r64;
#pragma unroll
        for (int l = 0; l < 32; l++) r32[l >> 3][l & 7] = __shfl(fr, l);
    }
    double loss_acc = 0.0;

    for (int i = 0; i < NVQ_; i++) {
        __syncthreads();   // all waves done reading en_s from previous stream
        {   // stage fp64 codebook -> fp32 LDS planes (8192 doubles -> 4096 float2)
            const double* src = en64g + (size_t)i * D_ * K_;
#pragma unroll
            for (int it = 0; it < 8; it++) {
                int c  = it * 512 + tid;      // 0..4095
                int dp = c >> 10, k = c & 1023;
                double a = src[(size_t)(2 * dp) * K_ + k];
                double b = src[(size_t)(2 * dp + 1) * K_ + k];
                en_s[dp * K_ + k] = make_float2((float)a, (float)b);
            }
        }
        __syncthreads();

        // fp32 screen: top-1 (value+index) and top-2 value per chain
        float smax[4], s2[4]; int sidx[4];
#pragma unroll
        for (int m = 0; m < 4; m++) { smax[m] = -FLT_MAX; s2[m] = -FLT_MAX; sidx[m] = 0; }
#pragma unroll 4
        for (int j = 0; j < 16; j++) {
            int k = j * 64 + lane;
            float2 c0 = en_s[k];
            float2 c1 = en_s[K_ + k];
            float2 c2 = en_s[2 * K_ + k];
            float2 c3 = en_s[3 * K_ + k];
            float cw[8] = {c0.x, c0.y, c1.x, c1.y, c2.x, c2.y, c3.x, c3.y};
#pragma unroll
            for (int m = 0; m < 4; m++) {
                float s = cw[0] * r32[m][0];
#pragma unroll
                for (int d = 1; d < 8; d++) s = fmaf(cw[d], r32[m][d], s);
                float lo = fminf(s, smax[m]);          // loser of (s, running max)
                s2[m] = fmaxf(s2[m], lo);
                if (s > smax[m]) { smax[m] = s; sidx[m] = k; }   // strict >: first index wins
            }
        }
        // cross-lane reduce (top-2 merge; first-index tie-break on top-1)
#pragma unroll
        for (int off = 32; off >= 1; off >>= 1) {
#pragma unroll
            for (int m = 0; m < 4; m++) {
                float om = __shfl_xor(smax[m], off);
                int   oi = __shfl_xor(sidx[m], off);
                float o2 = __shfl_xor(s2[m], off);
                s2[m] = fmaxf(fmaxf(s2[m], o2), fminf(smax[m], om));
                if (om > smax[m] || (om == smax[m] && oi < sidx[m])) { smax[m] = om; sidx[m] = oi; }
            }
        }
        // certify winner vs fp64; rescan exactly if the fp32 gap can't prove it.
        // |s32 - s64| <= ~10*2^-24*||r||; require gap > 4e-6*||r|| (3x margin):
        // gap^2 > 1.6e-11 * ||r||^2
#pragma unroll
        for (int m = 0; m < 4; m++) {
            float rr = 0.f;
#pragma unroll
            for (int d = 0; d < 8; d++) rr = fmaf(r32[m][d], r32[m][d], rr);
            float gap = smax[m] - s2[m];
            if (!(gap * gap > 1.6e-11f * rr)) {        // rare, wave-uniform
                double rm[8];
#pragma unroll
                for (int d = 0; d < 8; d++) rm[d] = __shfl(r64, m * 8 + d);
                const double* base = en64g + (size_t)i * D_ * K_;
                double bmax = -DBL_MAX; int bidx = 0;
                for (int j = 0; j < 16; j++) {
                    int k = j * 64 + lane;
                    double s = 0.0;
#pragma unroll
                    for (int d = 0; d < 8; d++) s = fma(base[(size_t)d * K_ + k], rm[d], s);
                    if (s > bmax) { bmax = s; bidx = k; }
                }
#pragma unroll
                for (int off = 32; off >= 1; off >>= 1) {
                    double om = __shfl_xor(bmax, off);
                    int    oi = __shfl_xor(bidx, off);
                    if (om > bmax || (om == bmax && oi < bidx)) { bmax = om; bidx = oi; }
                }
                sidx[m] = bidx;
            }
        }
        // exact distributed residual update + loss
        int mycode = lane < 8 ? sidx[0] : lane < 16 ? sidx[1] : lane < 24 ? sidx[2] : sidx[3];
        if (lane < 32) {
            double q = en64g[((size_t)i * D_ + (lane & 7)) * K_ + mycode];
            r64 -= q;
            loss_acc = fma(r64, r64, loss_acc);
        }
        if (lane == 0) {
#pragma unroll
            for (int m = 0; m < 4; m++) {
                int pos = mypos0 + m;
                int b = pos / T_, t = pos - b * T_;
                out_idx[((size_t)(b * NVQ_ + i) * G_ + g) * T_ + t] = (float)sidx[m];
            }
        }
        // refresh fp32 copy
        {
            float fr = (float)r64;
#pragma unroll
            for (int l = 0; l < 32; l++) r32[l >> 3][l & 7] = __shfl(fr, l);
        }
    }
    // zq = zd - r_final (distributed -> already one element per lane)
    if (lane < 32) zq[zdbase + lane] = (float)(zd0 - r64);
    // loss: wave tree-sum (lanes>=32 hold 0), per-block reduce, one fp64 atomic
#pragma unroll
    for (int off = 32; off >= 1; off >>= 1) loss_acc += __shfl_xor(loss_acc, off);
    if (lane == 0) ls[wv] = loss_acc;
    __syncthreads();
    if (tid == 0) {
        double s = 0.0;
#pragma unroll
        for (int w2 = 0; w2 < 8; w2++) s += ls[w2];
        atomicAdd(loss, s);
    }
}

// ---------------------------------------------------------------------------
// K4: proj_up + unfold scatter (fp32). 512 threads / 8 positions per block to
// halve the pu LDS-staging traffic vs the 4-position baseline.
__global__ __launch_bounds__(512) void k4_up(const float* __restrict__ zq,
                                             const float* __restrict__ pu,
                                             const double* __restrict__ loss,
                                             float* __restrict__ out_zq,
                                             float* __restrict__ out_loss) {
    __shared__ __align__(16) float pu_s[G_ * GD_ * 9];   // 54 KB, row stride 9
    int tid = threadIdx.x;
#pragma unroll
    for (int it = 0; it < 3; it++) {
        int row = it * 512 + tid;            // 0..1535
        float4 lo = *(const float4*)(pu + (size_t)row * 8);
        float4 hi = *(const float4*)(pu + (size_t)row * 8 + 4);
        float* dst = &pu_s[row * 9];
        dst[0] = lo.x; dst[1] = lo.y; dst[2] = lo.z; dst[3] = lo.w;
        dst[4] = hi.x; dst[5] = hi.y; dst[6] = hi.z; dst[7] = hi.w;
    }
    if (blockIdx.x == 0 && tid == 0) {
        double l = loss[0] * (1.0 / 460800.0);   // /(B*T*D) per group, /G
        out_loss[0] = (float)l;
        out_loss[1] = (float)l;
    }
    __syncthreads();
    int wv = tid >> 6, lane = tid & 63;
    int pos = blockIdx.x * 8 + wv;
    int b = pos / T_, t = pos - b * T_;
    int ov = lane >> 4, c0 = (lane & 15) * 4;
    int gd_min = ov * FIX_ + c0 * 6;
    int g_lo = gd_min >> 9;
    int g_hi = g_lo < 2 ? g_lo + 1 : 2;
    float za[8], zb[8];
    const float* zqa = zq + ((size_t)g_lo * NPOS_ + pos) * D_;
    const float* zqb = zq + ((size_t)g_hi * NPOS_ + pos) * D_;
#pragma unroll
    for (int d = 0; d < 8; d++) { za[d] = zqa[d]; zb[d] = zqb[d]; }
#pragma unroll
    for (int h = 0; h < H_; h++) {
        float4 o;
        float* op = &o.x;
#pragma unroll
        for (int q = 0; q < 4; q++) {
            int gd = ov * FIX_ + (c0 + q) * 6 + h;
            int g  = gd >> 9;
            int j  = gd & 511;
            const float* pr = &pu_s[(g * GD_ + j) * 9];
            bool hi = (g != g_lo);
            float acc = 0.f;
#pragma unroll
            for (int d = 0; d < 8; d++) {
                float zv = hi ? zb[d] : za[d];
                acc = fmaf(zv, pr[d], acc);
            }
            op[q] = acc;
        }
        *(float4*)(out_zq + ((size_t)((b * H_ + h) * W_ + 4 * t + ov)) * C_ + c0) = o;
    }
}

// ---------------------------------------------------------------------------
extern "C" void kernel_launch(void* const* d_in, const int* in_sizes, int n_in,
                              void* d_out, int out_size, void* d_ws, size_t ws_size,
                              hipStream_t stream) {
    const float* ze = (const float*)d_in[0];
    const float* pd = (const float*)d_in[1];
    const float* pu = (const float*)d_in[2];
    const float* cb = (const float*)d_in[3];
    // d_in[4] = num_streams (==6, compile-time NVQ_)

    float* out = (float*)d_out;
    char*  ws  = (char*)d_ws;
    double* ws_en   = (double*)(ws + WS_EN);
    double* ws_zd   = (double*)(ws + WS_ZD);
    double* ws_loss = (double*)(ws + WS_LOSS);
    float*  ws_zq   = (float*)(ws + WS_ZQ);

    k1_norm_cb<<<(G_ * NVQ_ * K_ + 255) / 256, 256, 0, stream>>>(cb, ws_en, ws_loss);
    k2_fold_pd<<<NPOS_ / 8, 256, 0, stream>>>(ze, pd, ws_zd);
    k3_rvq<<<G_ * (NPOS_ / 32), 512, 0, stream>>>(ws_en, ws_zd, ws_zq, ws_loss, out + OUT_IDX);
    k4_up<<<NPOS_ / 8, 512, 0, stream>>>(ws_zq, pu, ws_loss, out + OUT_ZQ, out + OUT_LOSS);
}